// Round 4
// baseline (95.420 us; speedup 1.0000x reference)
//
#include <hip/hip_runtime.h>

// GraphAttention — analytical result.
//
// The reference ends with:   out = elu(attn2 @ Wh2)   with shape (N, 1)
// followed by               log_softmax(out, axis=1)
// Axis 1 has size 1, so log_softmax(x) = x - logsumexp(x) = x - x = 0.0
// exactly, for every finite x. All intermediates are finite (inputs are
// Gaussian; every masked-softmax row contains the unmasked diagonal since
// adj is max'd with eye(N), so no NaN/Inf can arise). Therefore the
// reference output is identically a (4096, 1) tensor of exact 0.0f,
// independent of all inputs.
//
// The optimal kernel writes out_size zeros. d_out is re-poisoned to 0xAA
// before every timed launch, so the write must happen on every call (it
// does: single unconditional store kernel, no static guards).

__global__ void gat_zero_out_kernel(float* __restrict__ out, int n) {
    int i = blockIdx.x * blockDim.x + threadIdx.x;
    if (i < n) out[i] = 0.0f;
}

extern "C" void kernel_launch(void* const* d_in, const int* in_sizes, int n_in,
                              void* d_out, int out_size, void* d_ws, size_t ws_size,
                              hipStream_t stream) {
    (void)d_in; (void)in_sizes; (void)n_in; (void)d_ws; (void)ws_size;
    float* out = (float*)d_out;
    const int threads = 256;
    const int blocks = (out_size + threads - 1) / threads;  // 16 blocks for 4096
    gat_zero_out_kernel<<<blocks, threads, 0, stream>>>(out, out_size);
}